// Round 8
// baseline (243.658 us; speedup 1.0000x reference)
//
#include <hip/hip_runtime.h>
#include <hip/hip_bf16.h>
#include <math.h>

// B=4, C=256, N=4096, QP=32.
// ws: qH[b][n][32] f16 (PRE-SCALED by log2e), kH[b][n][32] f16,
//     vHT[b][c][n] f16, wH[320][256] f16 (Wq rows scaled), ms4[4][b][n] f32.
// K0 wprep: W->f16 (+log2e on Wq rows).
// K1 qkv: MFMA GEMM, 32-n tiles (512 blocks, 2 blk/CU).
// K2 mpass: partial col-max of S' (log2 domain).
// K3 attn: r6 sync structure (one __syncthreads/iter, block-wide contiguous
//   DMA) + r7 decomposition (8 waves = ch2 x ih4; wave owns 128c x 64j,
//   va A-frags reused across BOTH j-tiles -> LDS reads HALVED vs r6).
//   S duplicated x2 (ch pair) - the only duplication. S1 computed after
//   PV0 so S0/S1 never co-live (reg pressure). NO inline-asm waitcnt:
//   r7 showed LLVM's waitcnt pass goes conservative around opaque asm
//   (inserts vmcnt(0) -> drains just-issued DMA every iter, 1.75x loss).

#define NBATCH 4
#define CDIM   256
#define NSEQ   4096
#define QPDIM  32
#define LOG2E  1.44269504088896340736f

typedef _Float16 half8_t  __attribute__((ext_vector_type(8)));
typedef _Float16 half2_t  __attribute__((ext_vector_type(2)));
typedef float    floatx4  __attribute__((ext_vector_type(4)));
typedef float    floatx16 __attribute__((ext_vector_type(16)));

union H8 { half8_t h8; half2_t h2[4]; int i32[4]; };

__device__ inline half2_t pack_f16(float a, float b) {
    return __builtin_bit_cast(half2_t, __builtin_amdgcn_cvt_pkrtz(a, b));
}

// D-frag (rows = k) -> B-operand frags via permlane32_swap (or shfl fallback)
__device__ inline void transformP(const H8& lo, const H8& hi,
                                  H8& P0, H8& P1, const int l5) {
#if __has_builtin(__builtin_amdgcn_permlane32_swap)
    {
        auto r0p = __builtin_amdgcn_permlane32_swap(
            (unsigned)lo.i32[0], (unsigned)lo.i32[2], false, false);
        P0.i32[0] = (int)r0p[0]; P0.i32[2] = (int)r0p[1];
        auto r1p = __builtin_amdgcn_permlane32_swap(
            (unsigned)lo.i32[1], (unsigned)lo.i32[3], false, false);
        P0.i32[1] = (int)r1p[0]; P0.i32[3] = (int)r1p[1];
        auto r2p = __builtin_amdgcn_permlane32_swap(
            (unsigned)hi.i32[0], (unsigned)hi.i32[2], false, false);
        P1.i32[0] = (int)r2p[0]; P1.i32[2] = (int)r2p[1];
        auto r3p = __builtin_amdgcn_permlane32_swap(
            (unsigned)hi.i32[1], (unsigned)hi.i32[3], false, false);
        P1.i32[1] = (int)r3p[0]; P1.i32[3] = (int)r3p[1];
    }
#else
    {
        H8 shl, shh;
        #pragma unroll
        for (int r = 0; r < 4; ++r) {
            shl.i32[r] = __shfl_xor(lo.i32[r], 32);
            shh.i32[r] = __shfl_xor(hi.i32[r], 32);
        }
        const bool high = (l5 != 0);
        P0.i32[0] = high ? shl.i32[2] : lo.i32[0];
        P0.i32[1] = high ? shl.i32[3] : lo.i32[1];
        P0.i32[2] = high ? lo.i32[2]  : shl.i32[0];
        P0.i32[3] = high ? lo.i32[3]  : shl.i32[1];
        P1.i32[0] = high ? shh.i32[2] : hi.i32[0];
        P1.i32[1] = high ? shh.i32[3] : hi.i32[1];
        P1.i32[2] = high ? hi.i32[2]  : shh.i32[0];
        P1.i32[3] = high ? hi.i32[3]  : shh.i32[1];
    }
#endif
}

// ---------------------------------------------------------------------------
// K0: W -> f16, Wq rows scaled by log2e. 40 blocks x 256 thr x 8 elems.
// ---------------------------------------------------------------------------
__global__ __launch_bounds__(256) void wprep_kernel(
    const float* __restrict__ Wv, const float* __restrict__ Wq,
    const float* __restrict__ Wk, _Float16* __restrict__ wH)
{
    const int idx = blockIdx.x * 256 + threadIdx.x;
    const int e = idx * 8;
    const int r = e >> 8, c = e & 255;
    const float* src;
    float scale = 1.0f;
    if (r < 256)      src = Wv + (size_t)r * 256 + c;
    else if (r < 288) { src = Wq + (size_t)(r - 256) * 256 + c; scale = LOG2E; }
    else              src = Wk + (size_t)(r - 288) * 256 + c;
    float4 f0 = ((const float4*)src)[0];
    float4 f1 = ((const float4*)src)[1];
    half8_t h;
    h[0] = (_Float16)(f0.x * scale); h[1] = (_Float16)(f0.y * scale);
    h[2] = (_Float16)(f0.z * scale); h[3] = (_Float16)(f0.w * scale);
    h[4] = (_Float16)(f1.x * scale); h[5] = (_Float16)(f1.y * scale);
    h[6] = (_Float16)(f1.z * scale); h[7] = (_Float16)(f1.w * scale);
    *(half8_t*)(wH + (size_t)r * 256 + c) = h;
}

// ---------------------------------------------------------------------------
// K1: qkv GEMM. grid = 4b x 128 nt(32 n) = 512 blocks, 256 thr (4 waves).
// ---------------------------------------------------------------------------
__global__ __launch_bounds__(256, 2) void qkv_kernel(
    const float* __restrict__ x, const _Float16* __restrict__ wH,
    const float* __restrict__ bq, const float* __restrict__ bk,
    const float* __restrict__ bv,
    _Float16* __restrict__ qH, _Float16* __restrict__ kH,
    _Float16* __restrict__ vHT)
{
    __shared__ _Float16 xT[32][264];   // [n][c]

    const int blk  = blockIdx.x;
    const int slot = blk & 7;
    const int b    = slot >> 1;
    const int n0   = (((blk >> 3) << 1) | (slot & 1)) << 5;  // 32-n tile
    const int t    = threadIdx.x;
    const int w    = t >> 6;
    const int lane = t & 63;
    const int quad = lane >> 4;
    const int col  = lane & 15;

    // ---- stage x[b, :, n0..n0+31] transposed -> f16 ----
    {
        const int crow0 = t >> 3;          // 0..31
        const int npart = t & 7;           // 8 lanes sweep 32 n
        #pragma unroll
        for (int pass = 0; pass < 8; ++pass) {
            const int c = pass * 32 + crow0;
            float4 f = *(const float4*)(
                x + ((size_t)(b * CDIM + c)) * NSEQ + n0 + npart * 4);
            xT[npart * 4 + 0][c] = (_Float16)f.x;
            xT[npart * 4 + 1][c] = (_Float16)f.y;
            xT[npart * 4 + 2][c] = (_Float16)f.z;
            xT[npart * 4 + 3][c] = (_Float16)f.w;
        }
    }
    __syncthreads();

    // ---- GEMM: wave w -> rows w*80 .. +79 (5 m-tiles of 16), 32 n ----
    const int r0 = w * 80;
    floatx4 acc[5][2];
    #pragma unroll
    for (int mt = 0; mt < 5; ++mt)
        #pragma unroll
        for (int nt = 0; nt < 2; ++nt)
            acc[mt][nt] = (floatx4){0.f, 0.f, 0.f, 0.f};

    #pragma unroll
    for (int ks = 0; ks < 8; ++ks) {
        half8_t bf[2];
        #pragma unroll
        for (int nt = 0; nt < 2; ++nt)
            bf[nt] = *(const half8_t*)&xT[nt * 16 + col][ks * 32 + quad * 8];
        #pragma unroll
        for (int mt = 0; mt < 5; ++mt) {
            half8_t a = *(const half8_t*)(
                wH + (size_t)(r0 + mt * 16 + col) * 256 + ks * 32 + quad * 8);
            #pragma unroll
            for (int nt = 0; nt < 2; ++nt)
                acc[mt][nt] = __builtin_amdgcn_mfma_f32_16x16x32_f16(
                    a, bf[nt], acc[mt][nt], 0, 0, 0);
        }
    }

    // ---- epilogue ----
    #pragma unroll
    for (int mt = 0; mt < 5; ++mt) {
        const int gbase = r0 + mt * 16;
        const float* bp; int rl; float bscale = 1.0f;
        if (gbase < 256)      { bp = bv; rl = gbase; }
        else if (gbase < 288) { bp = bq; rl = gbase - 256; bscale = LOG2E; }
        else                  { bp = bk; rl = gbase - 288; }
        #pragma unroll
        for (int reg = 0; reg < 4; ++reg) {
            const int rr = rl + quad * 4 + reg;
            const float bias = bp[rr] * bscale;
            #pragma unroll
            for (int nt = 0; nt < 2; ++nt) {
                const int n = n0 + nt * 16 + col;
                const float val = acc[mt][nt][reg] + bias;
                if (gbase < 256)
                    vHT[((size_t)(b * CDIM + rr)) * NSEQ + n] = (_Float16)val;
                else if (gbase < 288)
                    qH[((size_t)(b * NSEQ + n)) * QPDIM + rr] = (_Float16)val;
                else
                    kH[((size_t)(b * NSEQ + n)) * QPDIM + rr] = (_Float16)val;
            }
        }
    }
}

// ---------------------------------------------------------------------------
// K2: mpass partial col-max (log2 domain). grid = 4iq x 4b x 64 jblk = 1024.
// ---------------------------------------------------------------------------
__global__ __launch_bounds__(256, 4) void mpass_kernel(
    const _Float16* __restrict__ qH, const _Float16* __restrict__ kH,
    float* __restrict__ ms4)
{
    __shared__ float wmax[4][32];

    const int blk  = blockIdx.x;
    const int slot = blk & 7;
    const int b    = slot >> 1;
    const int idx  = ((blk >> 3) << 1) | (slot & 1);
    const int jblk = idx & 63;
    const int iq   = idx >> 6;
    const int t    = threadIdx.x;
    const int w    = t >> 6;
    const int lane = t & 63;
    const int l5   = lane >> 5;
    const int lj   = lane & 31;
    const int jt   = w & 1, ih = w >> 1;

    const _Float16* qg = qH + (size_t)b * NSEQ * QPDIM;
    const int j = jblk * 64 + jt * 32 + lj;
    const half8_t kb0 = *(const half8_t*)(
        kH + ((size_t)(b * NSEQ + j)) * QPDIM + l5 * 8);
    const half8_t kb1 = *(const half8_t*)(
        kH + ((size_t)(b * NSEQ + j)) * QPDIM + 16 + l5 * 8);

    float mx = -1e30f;
    const int ibase = iq * 1024 + ih * 512;
    for (int cc = 0; cc < 16; ++cc) {
        const _Float16* qp = qg + (size_t)(ibase + cc * 32 + lj) * QPDIM + l5 * 8;
        half8_t qa0 = *(const half8_t*)qp;
        half8_t qa1 = *(const half8_t*)(qp + 16);
        floatx16 S = __builtin_amdgcn_mfma_f32_32x32x16_f16(
            qa0, kb0, (floatx16){0.f}, 0, 0, 0);
        S = __builtin_amdgcn_mfma_f32_32x32x16_f16(qa1, kb1, S, 0, 0, 0);
        #pragma unroll
        for (int r = 0; r < 16; ++r) mx = fmaxf(mx, S[r]);
    }
    mx = fmaxf(mx, __shfl_xor(mx, 32));
    if (lane < 32) wmax[w][lane] = mx;
    __syncthreads();
    if (t < 64) {
        const int jt3 = t >> 5, c = t & 31;
        ms4[(size_t)iq * (NBATCH * NSEQ) + (size_t)b * NSEQ
            + jblk * 64 + jt3 * 32 + c] = fmaxf(wmax[jt3][c], wmax[jt3 + 2][c]);
    }
}

// ---------------------------------------------------------------------------
// K3: attn. grid = 256 (4b x 64 jblk), 512 thr (8 waves = ch2 x ih4).
// One barrier per 128-i tile; block-wide contiguous DMA (r6 pattern);
// wave (ch,ih) computes S for BOTH 32-j tiles and PV over its 128-c half,
// reusing each va A-frag across the two j-tiles (LDS reads halved vs r6).
// ---------------------------------------------------------------------------
__global__ __launch_bounds__(512, 1) void attn_kernel(
    const _Float16* __restrict__ qH, const _Float16* __restrict__ kH,
    const _Float16* __restrict__ vHT, const float* __restrict__ ms4,
    const float* __restrict__ x, const float* __restrict__ gamma,
    float* __restrict__ out)
{
    __shared__ _Float16 vbuf[2][32768];  // [buf][4096 units of 16B] (128 KB)
    __shared__ float lred[4][64];        // [ih][j] denominator partials

    const int blk  = blockIdx.x;
    const int slot = blk & 7;
    const int b    = slot >> 1;
    const int jblk = ((blk >> 3) << 1) | (slot & 1);  // 0..63
    const int j0   = jblk << 6;
    const int t    = threadIdx.x;
    const int w    = t >> 6;                          // 0..7
    const int lane = t & 63;
    const int l5   = lane >> 5;
    const int lj   = lane & 31;
    const int ch   = w & 1;                           // c-half (128 c)
    const int ih   = w >> 1;                          // 0..3 (32-i slice)

    const _Float16* qg = qH + (size_t)b * NSEQ * QPDIM;
    const _Float16* vg = vHT + (size_t)b * CDIM * NSEQ;

    // K frags + mfix for BOTH j-tiles (j = j0+lj and j0+32+lj)
    const int jme0 = j0 + lj;
    const int jme1 = j0 + 32 + lj;
    const half8_t kbA0 = *(const half8_t*)(
        kH + ((size_t)(b * NSEQ + jme0)) * QPDIM + l5 * 8);
    const half8_t kbB0 = *(const half8_t*)(
        kH + ((size_t)(b * NSEQ + jme0)) * QPDIM + 16 + l5 * 8);
    const half8_t kbA1 = *(const half8_t*)(
        kH + ((size_t)(b * NSEQ + jme1)) * QPDIM + l5 * 8);
    const half8_t kbB1 = *(const half8_t*)(
        kH + ((size_t)(b * NSEQ + jme1)) * QPDIM + 16 + l5 * 8);

    const float* msb0 = ms4 + (size_t)b * NSEQ + jme0;
    const float mf0 = fmaxf(
        fmaxf(msb0[0], msb0[NBATCH * NSEQ]),
        fmaxf(msb0[2 * NBATCH * NSEQ], msb0[3 * NBATCH * NSEQ]));
    const float* msb1 = ms4 + (size_t)b * NSEQ + jme1;
    const float mf1 = fmaxf(
        fmaxf(msb1[0], msb1[NBATCH * NSEQ]),
        fmaxf(msb1[2 * NBATCH * NSEQ], msb1[3 * NBATCH * NSEQ]));

    floatx16 acc[4][2];
    #pragma unroll
    for (int ct = 0; ct < 4; ++ct)
        #pragma unroll
        for (int jt = 0; jt < 2; ++jt) acc[ct][jt] = (floatx16){0.f};
    float lp0 = 0.0f, lp1 = 0.0f;

    // v DMA (r6 pattern): block covers 256 c-rows x 16 chunks (128 i),
    // contiguous 256 B per row. Wave w: units [w*512, +512).
    #define DMA_V(i0_, buf_)                                                   \
        {                                                                      \
            _Pragma("unroll")                                                  \
            for (int g = 0; g < 8; ++g) {                                      \
                const int uu = w * 512 + g * 64 + lane;                        \
                const int cl = uu >> 4;                                        \
                const int ck = (uu & 15) ^ (cl & 7);                           \
                const _Float16* src =                                          \
                    vg + (size_t)cl * NSEQ + (i0_) + ck * 8;                   \
                __builtin_amdgcn_global_load_lds(                              \
                    (const __attribute__((address_space(1))) void*)src,        \
                    (__attribute__((address_space(3))) void*)                  \
                        (&vbuf[buf_][(w * 512 + g * 64) * 8]),                 \
                    16, 0, 0);                                                 \
            }                                                                  \
        }

    DMA_V(0, 0);
    const _Float16* qb = qg + (size_t)(ih * 32 + lj) * QPDIM + l5 * 8;
    half8_t qa0 = *(const half8_t*)(qb);
    half8_t qa1 = *(const half8_t*)(qb + 16);

    int cur = 0;
    for (int i0 = 0; i0 < NSEQ; i0 += 128) {
        __syncthreads();   // vbuf[cur] DMA'd (issued 1 iter ago); prev reads done
        if (i0 + 128 < NSEQ) DMA_V(i0 + 128, cur ^ 1);

        // ---- va A-frags: 8 reads, each reused by BOTH j-tiles ----
        half8_t va[4][2];
        #pragma unroll
        for (int ct = 0; ct < 4; ++ct) {
            const int cl = ch * 128 + ct * 32 + lj;
            const int sw = cl & 7;
            const int ic0 = (ih * 4 + 0 + l5) ^ sw;
            const int ic1 = (ih * 4 + 2 + l5) ^ sw;
            va[ct][0] = *(const half8_t*)&vbuf[cur][(cl * 16 + ic0) * 8];
            va[ct][1] = *(const half8_t*)&vbuf[cur][(cl * 16 + ic1) * 8];
        }

        // ---- jt0: S -> exp2 -> P -> PV into acc[*][0] ----
        {
            floatx16 S = __builtin_amdgcn_mfma_f32_32x32x16_f16(
                qa0, kbA0, (floatx16){0.f}, 0, 0, 0);
            S = __builtin_amdgcn_mfma_f32_32x32x16_f16(qa1, kbB0, S, 0, 0, 0);
            H8 lo, hi;
            float ls = 0.0f;
            #pragma unroll
            for (int p = 0; p < 4; ++p) {
                float pa = __builtin_amdgcn_exp2f(S[2 * p]     - mf0);
                float pb = __builtin_amdgcn_exp2f(S[2 * p + 1] - mf0);
                ls += pa + pb;
                lo.h2[p] = pack_f16(pa, pb);
            }
            #pragma unroll
            for (int p = 0; p < 4; ++p) {
                float pa = __builtin_amdgcn_exp2f(S[8 + 2 * p]     - mf0);
                float pb = __builtin_amdgcn_exp2f(S[8 + 2 * p + 1] - mf0);
                ls += pa + pb;
                hi.h2[p] = pack_f16(pa, pb);
            }
            lp0 += ls;
            H8 Pa, Pb;
            transformP(lo, hi, Pa, Pb, l5);
            __builtin_amdgcn_s_setprio(1);
            #pragma unroll
            for (int ct = 0; ct < 4; ++ct) {
                acc[ct][0] = __builtin_amdgcn_mfma_f32_32x32x16_f16(
                    va[ct][0], Pa.h8, acc[ct][0], 0, 0, 0);
                acc[ct][0] = __builtin_amdgcn_mfma_f32_32x32x16_f16(
                    va[ct][1], Pb.h8, acc[ct][0], 0, 0, 0);
            }
            __builtin_amdgcn_s_setprio(0);
        }

        // ---- jt1: S -> exp2 -> P -> PV into acc[*][1] ----
        {
            floatx16 S = __builtin_amdgcn_mfma_f32_32x32x16_f16(
                qa0, kbA1, (floatx16){0.f}, 0, 0, 0);
            S = __builtin_amdgcn_mfma_f32_32x32x16_f16(qa1, kbB1, S, 0, 0, 0);
            H8 lo, hi;
            float ls = 0.0f;
            #pragma unroll
            for (int p = 0; p < 4; ++p) {
                float pa = __builtin_amdgcn_exp2f(S[2 * p]     - mf1);
                float pb = __builtin_amdgcn_exp2f(S[2 * p + 1] - mf1);
                ls += pa + pb;
                lo.h2[p] = pack_f16(pa, pb);
            }
            #pragma unroll
            for (int p = 0; p < 4; ++p) {
                float pa = __builtin_amdgcn_exp2f(S[8 + 2 * p]     - mf1);
                float pb = __builtin_amdgcn_exp2f(S[8 + 2 * p + 1] - mf1);
                ls += pa + pb;
                hi.h2[p] = pack_f16(pa, pb);
            }
            lp1 += ls;
            H8 Pa, Pb;
            transformP(lo, hi, Pa, Pb, l5);
            __builtin_amdgcn_s_setprio(1);
            #pragma unroll
            for (int ct = 0; ct < 4; ++ct) {
                acc[ct][1] = __builtin_amdgcn_mfma_f32_32x32x16_f16(
                    va[ct][0], Pa.h8, acc[ct][1], 0, 0, 0);
                acc[ct][1] = __builtin_amdgcn_mfma_f32_32x32x16_f16(
                    va[ct][1], Pb.h8, acc[ct][1], 0, 0, 0);
            }
            __builtin_amdgcn_s_setprio(0);
        }

        // prefetch next q frags (drained by next barrier)
        if (i0 + 128 < NSEQ) {
            qa0 = *(const half8_t*)(qb + (size_t)(i0 + 128) * QPDIM);
            qa1 = *(const half8_t*)(qb + (size_t)(i0 + 128) * QPDIM + 16);
        }
        cur ^= 1;
    }

    // ---- denominator partials (ch==0 waves only; S duplicated on ch==1) ----
    lp0 += __shfl_xor(lp0, 32);
    lp1 += __shfl_xor(lp1, 32);
    if (ch == 0 && lane < 32) {
        lred[ih][lane]      = lp0;
        lred[ih][32 + lane] = lp1;
    }
    __syncthreads();   // all PV reads of vbuf done before fred overwrite

    // ---- 2-round merge across ih in fred = vbuf (4 regions x 8192 f32) ----
    float* fred = (float*)vbuf;
    if (ih & 1) {
        float* rg = fred + (ch * 2 + (ih >> 1)) * 8192;
        #pragma unroll
        for (int ct = 0; ct < 4; ++ct)
            #pragma unroll
            for (int jt = 0; jt < 2; ++jt)
                #pragma unroll
                for (int reg = 0; reg < 16; ++reg) {
                    const int crow = (reg & 3) + 8 * (reg >> 2) + 4 * l5;
                    rg[((ct * 2 + jt) * 32 + crow) * 32 + lj] = acc[ct][jt][reg];
                }
    }
    __syncthreads();
    if (!(ih & 1)) {
        float* rg = fred + (ch * 2 + (ih >> 1)) * 8192;
        #pragma unroll
        for (int ct = 0; ct < 4; ++ct)
            #pragma unroll
            for (int jt = 0; jt < 2; ++jt)
                #pragma unroll
                for (int reg = 0; reg < 16; ++reg) {
                    const int crow = (reg & 3) + 8 * (reg >> 2) + 4 * l5;
                    acc[ct][jt][reg] += rg[((ct * 2 + jt) * 32 + crow) * 32 + lj];
                }
    }
    __syncthreads();
    // Round B: ih0 writes ct 2,3 -> R(ch,0); ih2 writes ct 0,1 -> R(ch,1)
    if (ih == 0) {
        float* rg = fred + (ch * 2 + 0) * 8192;
        #pragma unroll
        for (int ct = 2; ct < 4; ++ct)
            #pragma unroll
            for (int jt = 0; jt < 2; ++jt)
                #pragma unroll
                for (int reg = 0; reg < 16; ++reg) {
                    const int crow = (reg & 3) + 8 * (reg >> 2) + 4 * l5;
                    rg[(((ct - 2) * 2 + jt) * 32 + crow) * 32 + lj] =
                        acc[ct][jt][reg];
                }
    } else if (ih == 2) {
        float* rg = fred + (ch * 2 + 1) * 8192;
        #pragma unroll
        for (int ct = 0; ct < 2; ++ct)
            #pragma unroll
            for (int jt = 0; jt < 2; ++jt)
                #pragma unroll
                for (int reg = 0; reg < 16; ++reg) {
                    const int crow = (reg & 3) + 8 * (reg >> 2) + 4 * l5;
                    rg[((ct * 2 + jt) * 32 + crow) * 32 + lj] = acc[ct][jt][reg];
                }
    }
    __syncthreads();
    // Final: ih0 stores ct 0,1 (+ ih2's half); ih2 stores ct 2,3 (+ ih0's)
    if (ih == 0) {
        const float l0 = lred[0][lj] + lred[1][lj] + lred[2][lj] + lred[3][lj];
        const float l1 = lred[0][32 + lj] + lred[1][32 + lj]
                       + lred[2][32 + lj] + lred[3][32 + lj];
        const float rv0 = gamma[0] / l0;
        const float rv1 = gamma[0] / l1;
        float* rg = fred + (ch * 2 + 1) * 8192;
        #pragma unroll
        for (int ct = 0; ct < 2; ++ct)
            #pragma unroll
            for (int jt = 0; jt < 2; ++jt)
                #pragma unroll
                for (int reg = 0; reg < 16; ++reg) {
                    const int crow = (reg & 3) + 8 * (reg >> 2) + 4 * l5;
                    const int c_ = ch * 128 + ct * 32 + crow;
                    const int j_ = jt ? jme1 : jme0;
                    const size_t off = ((size_t)(b * CDIM + c_)) * NSEQ + j_;
                    const float sum = acc[ct][jt][reg]
                        + rg[((ct * 2 + jt) * 32 + crow) * 32 + lj];
                    out[off] = sum * (jt ? rv1 : rv0) + x[off];
                }
    } else if (ih == 2) {
        const float l0 = lred[0][lj] + lred[1][lj] + lred[2][lj] + lred[3][lj];
        const float l1 = lred[0][32 + lj] + lred[1][32 + lj]
                       + lred[2][32 + lj] + lred[3][32 + lj];
        const float rv0 = gamma[0] / l0;
        const float rv1 = gamma[0] / l1;
        float* rg = fred + (ch * 2 + 0) * 8192;
        #pragma unroll
        for (int ct = 2; ct < 4; ++ct)
            #pragma unroll
            for (int jt = 0; jt < 2; ++jt)
                #pragma unroll
                for (int reg = 0; reg < 16; ++reg) {
                    const int crow = (reg & 3) + 8 * (reg >> 2) + 4 * l5;
                    const int c_ = ch * 128 + ct * 32 + crow;
                    const int j_ = jt ? jme1 : jme0;
                    const size_t off = ((size_t)(b * CDIM + c_)) * NSEQ + j_;
                    const float sum = acc[ct][jt][reg]
                        + rg[(((ct - 2) * 2 + jt) * 32 + crow) * 32 + lj];
                    out[off] = sum * (jt ? rv1 : rv0) + x[off];
                }
    }
}

extern "C" void kernel_launch(void* const* d_in, const int* in_sizes, int n_in,
                              void* d_out, int out_size, void* d_ws, size_t ws_size,
                              hipStream_t stream) {
    const float* x     = (const float*)d_in[0];
    const float* Wq    = (const float*)d_in[1];
    const float* bq    = (const float*)d_in[2];
    const float* Wk    = (const float*)d_in[3];
    const float* bk    = (const float*)d_in[4];
    const float* Wv    = (const float*)d_in[5];
    const float* bv    = (const float*)d_in[6];
    const float* gamma = (const float*)d_in[7];
    float* out = (float*)d_out;

    _Float16* w16 = (_Float16*)d_ws;
    _Float16* qH  = w16;                                        // 1 MB
    _Float16* kH  = qH + (size_t)NBATCH * NSEQ * QPDIM;         // 1 MB
    _Float16* vHT = kH + (size_t)NBATCH * NSEQ * QPDIM;         // 8 MB
    _Float16* wH  = vHT + (size_t)NBATCH * CDIM * NSEQ;         // 160 KB
    float*    ms4 = (float*)(wH + (size_t)320 * 256);           // 256 KB

    wprep_kernel<<<40, 256, 0, stream>>>(Wv, Wq, Wk, wH);
    qkv_kernel<<<512, 256, 0, stream>>>(x, wH, bq, bk, bv, qH, kH, vHT);
    mpass_kernel<<<1024, 256, 0, stream>>>(qH, kH, ms4);
    attn_kernel<<<256, 512, 0, stream>>>(qH, kH, vHT, ms4, x, gamma, out);
}

// Round 9
// 234.288 us; speedup vs baseline: 1.0400x; 1.0400x over previous
//
#include <hip/hip_runtime.h>
#include <hip/hip_bf16.h>
#include <math.h>

// B=4, C=256, N=4096, QP=32.
// ws: qH[b][n][32] f16 (PRE-SCALED by log2e), kH[b][n][32] f16,
//     vHT[b][c][n] f16, wH[320][256] f16 (Wq rows scaled), ms4[4][b][n] f32.
// K0 wprep: W->f16 (+log2e on Wq rows).
// K1 qkv: MFMA GEMM, 32-n tiles (512 blocks, 2 blk/CU).
// K2 mpass: partial col-max of S' (log2 domain).
// K3 attn: NO V-STAGING (V is L2-resident: 2 MB/batch vs 4 MiB/XCD L2, and
//   the blk&7 slot map pins each XCD to one batch). va A-frags loaded
//   straight from global (16B/lane, L2 hits) -> no vbuf, no DMA, no bank
//   conflicts, ZERO barriers in main loop (waves free-run; r6's 8-wave
//   barrier convoy was ~45% of its time). grid 512 = 4b x 64jblk x 2jh,
//   256 thr (4 waves = ih4), 2 blk/CU. Per wave/iter: r6's exact work
//   (2 S-MFMA + 16 exp2 + permlane transform + 16 PV-MFMA, acc[8]).
//   S zero-dup. LDS = 64 KB epilogue merge only. va loads in 2 batches
//   of 8 (2nd batch in flight under PV half 1) -> peak regs ~240 < 256.
//   All acc indexing literal (rule #20; r5 scratch lesson).

#define NBATCH 4
#define CDIM   256
#define NSEQ   4096
#define QPDIM  32
#define LOG2E  1.44269504088896340736f

typedef _Float16 half8_t  __attribute__((ext_vector_type(8)));
typedef _Float16 half2_t  __attribute__((ext_vector_type(2)));
typedef float    floatx4  __attribute__((ext_vector_type(4)));
typedef float    floatx16 __attribute__((ext_vector_type(16)));

union H8 { half8_t h8; half2_t h2[4]; int i32[4]; };

__device__ inline half2_t pack_f16(float a, float b) {
    return __builtin_bit_cast(half2_t, __builtin_amdgcn_cvt_pkrtz(a, b));
}

// D-frag (rows = k) -> B-operand frags via permlane32_swap (or shfl fallback)
__device__ inline void transformP(const H8& lo, const H8& hi,
                                  H8& P0, H8& P1, const int l5) {
#if __has_builtin(__builtin_amdgcn_permlane32_swap)
    {
        auto r0p = __builtin_amdgcn_permlane32_swap(
            (unsigned)lo.i32[0], (unsigned)lo.i32[2], false, false);
        P0.i32[0] = (int)r0p[0]; P0.i32[2] = (int)r0p[1];
        auto r1p = __builtin_amdgcn_permlane32_swap(
            (unsigned)lo.i32[1], (unsigned)lo.i32[3], false, false);
        P0.i32[1] = (int)r1p[0]; P0.i32[3] = (int)r1p[1];
        auto r2p = __builtin_amdgcn_permlane32_swap(
            (unsigned)hi.i32[0], (unsigned)hi.i32[2], false, false);
        P1.i32[0] = (int)r2p[0]; P1.i32[2] = (int)r2p[1];
        auto r3p = __builtin_amdgcn_permlane32_swap(
            (unsigned)hi.i32[1], (unsigned)hi.i32[3], false, false);
        P1.i32[1] = (int)r3p[0]; P1.i32[3] = (int)r3p[1];
    }
#else
    {
        H8 shl, shh;
        #pragma unroll
        for (int r = 0; r < 4; ++r) {
            shl.i32[r] = __shfl_xor(lo.i32[r], 32);
            shh.i32[r] = __shfl_xor(hi.i32[r], 32);
        }
        const bool high = (l5 != 0);
        P0.i32[0] = high ? shl.i32[2] : lo.i32[0];
        P0.i32[1] = high ? shl.i32[3] : lo.i32[1];
        P0.i32[2] = high ? lo.i32[2]  : shl.i32[0];
        P0.i32[3] = high ? lo.i32[3]  : shl.i32[1];
        P1.i32[0] = high ? shh.i32[2] : hi.i32[0];
        P1.i32[1] = high ? shh.i32[3] : hi.i32[1];
        P1.i32[2] = high ? hi.i32[2]  : shh.i32[0];
        P1.i32[3] = high ? hi.i32[3]  : shh.i32[1];
    }
#endif
}

// ---------------------------------------------------------------------------
// K0: W -> f16, Wq rows scaled by log2e. 40 blocks x 256 thr x 8 elems.
// ---------------------------------------------------------------------------
__global__ __launch_bounds__(256) void wprep_kernel(
    const float* __restrict__ Wv, const float* __restrict__ Wq,
    const float* __restrict__ Wk, _Float16* __restrict__ wH)
{
    const int idx = blockIdx.x * 256 + threadIdx.x;
    const int e = idx * 8;
    const int r = e >> 8, c = e & 255;
    const float* src;
    float scale = 1.0f;
    if (r < 256)      src = Wv + (size_t)r * 256 + c;
    else if (r < 288) { src = Wq + (size_t)(r - 256) * 256 + c; scale = LOG2E; }
    else              src = Wk + (size_t)(r - 288) * 256 + c;
    float4 f0 = ((const float4*)src)[0];
    float4 f1 = ((const float4*)src)[1];
    half8_t h;
    h[0] = (_Float16)(f0.x * scale); h[1] = (_Float16)(f0.y * scale);
    h[2] = (_Float16)(f0.z * scale); h[3] = (_Float16)(f0.w * scale);
    h[4] = (_Float16)(f1.x * scale); h[5] = (_Float16)(f1.y * scale);
    h[6] = (_Float16)(f1.z * scale); h[7] = (_Float16)(f1.w * scale);
    *(half8_t*)(wH + (size_t)r * 256 + c) = h;
}

// ---------------------------------------------------------------------------
// K1: qkv GEMM. grid = 4b x 128 nt(32 n) = 512 blocks, 256 thr (4 waves).
// ---------------------------------------------------------------------------
__global__ __launch_bounds__(256, 2) void qkv_kernel(
    const float* __restrict__ x, const _Float16* __restrict__ wH,
    const float* __restrict__ bq, const float* __restrict__ bk,
    const float* __restrict__ bv,
    _Float16* __restrict__ qH, _Float16* __restrict__ kH,
    _Float16* __restrict__ vHT)
{
    __shared__ _Float16 xT[32][264];   // [n][c]

    const int blk  = blockIdx.x;
    const int slot = blk & 7;
    const int b    = slot >> 1;
    const int n0   = (((blk >> 3) << 1) | (slot & 1)) << 5;  // 32-n tile
    const int t    = threadIdx.x;
    const int w    = t >> 6;
    const int lane = t & 63;
    const int quad = lane >> 4;
    const int col  = lane & 15;

    // ---- stage x[b, :, n0..n0+31] transposed -> f16 ----
    {
        const int crow0 = t >> 3;          // 0..31
        const int npart = t & 7;           // 8 lanes sweep 32 n
        #pragma unroll
        for (int pass = 0; pass < 8; ++pass) {
            const int c = pass * 32 + crow0;
            float4 f = *(const float4*)(
                x + ((size_t)(b * CDIM + c)) * NSEQ + n0 + npart * 4);
            xT[npart * 4 + 0][c] = (_Float16)f.x;
            xT[npart * 4 + 1][c] = (_Float16)f.y;
            xT[npart * 4 + 2][c] = (_Float16)f.z;
            xT[npart * 4 + 3][c] = (_Float16)f.w;
        }
    }
    __syncthreads();

    // ---- GEMM: wave w -> rows w*80 .. +79 (5 m-tiles of 16), 32 n ----
    const int r0 = w * 80;
    floatx4 acc[5][2];
    #pragma unroll
    for (int mt = 0; mt < 5; ++mt)
        #pragma unroll
        for (int nt = 0; nt < 2; ++nt)
            acc[mt][nt] = (floatx4){0.f, 0.f, 0.f, 0.f};

    #pragma unroll
    for (int ks = 0; ks < 8; ++ks) {
        half8_t bf[2];
        #pragma unroll
        for (int nt = 0; nt < 2; ++nt)
            bf[nt] = *(const half8_t*)&xT[nt * 16 + col][ks * 32 + quad * 8];
        #pragma unroll
        for (int mt = 0; mt < 5; ++mt) {
            half8_t a = *(const half8_t*)(
                wH + (size_t)(r0 + mt * 16 + col) * 256 + ks * 32 + quad * 8);
            #pragma unroll
            for (int nt = 0; nt < 2; ++nt)
                acc[mt][nt] = __builtin_amdgcn_mfma_f32_16x16x32_f16(
                    a, bf[nt], acc[mt][nt], 0, 0, 0);
        }
    }

    // ---- epilogue ----
    #pragma unroll
    for (int mt = 0; mt < 5; ++mt) {
        const int gbase = r0 + mt * 16;
        const float* bp; int rl; float bscale = 1.0f;
        if (gbase < 256)      { bp = bv; rl = gbase; }
        else if (gbase < 288) { bp = bq; rl = gbase - 256; bscale = LOG2E; }
        else                  { bp = bk; rl = gbase - 288; }
        #pragma unroll
        for (int reg = 0; reg < 4; ++reg) {
            const int rr = rl + quad * 4 + reg;
            const float bias = bp[rr] * bscale;
            #pragma unroll
            for (int nt = 0; nt < 2; ++nt) {
                const int n = n0 + nt * 16 + col;
                const float val = acc[mt][nt][reg] + bias;
                if (gbase < 256)
                    vHT[((size_t)(b * CDIM + rr)) * NSEQ + n] = (_Float16)val;
                else if (gbase < 288)
                    qH[((size_t)(b * NSEQ + n)) * QPDIM + rr] = (_Float16)val;
                else
                    kH[((size_t)(b * NSEQ + n)) * QPDIM + rr] = (_Float16)val;
            }
        }
    }
}

// ---------------------------------------------------------------------------
// K2: mpass partial col-max (log2 domain). grid = 4iq x 4b x 64 jblk = 1024.
// ---------------------------------------------------------------------------
__global__ __launch_bounds__(256, 4) void mpass_kernel(
    const _Float16* __restrict__ qH, const _Float16* __restrict__ kH,
    float* __restrict__ ms4)
{
    __shared__ float wmax[4][32];

    const int blk  = blockIdx.x;
    const int slot = blk & 7;
    const int b    = slot >> 1;
    const int idx  = ((blk >> 3) << 1) | (slot & 1);
    const int jblk = idx & 63;
    const int iq   = idx >> 6;
    const int t    = threadIdx.x;
    const int w    = t >> 6;
    const int lane = t & 63;
    const int l5   = lane >> 5;
    const int lj   = lane & 31;
    const int jt   = w & 1, ih = w >> 1;

    const _Float16* qg = qH + (size_t)b * NSEQ * QPDIM;
    const int j = jblk * 64 + jt * 32 + lj;
    const half8_t kb0 = *(const half8_t*)(
        kH + ((size_t)(b * NSEQ + j)) * QPDIM + l5 * 8);
    const half8_t kb1 = *(const half8_t*)(
        kH + ((size_t)(b * NSEQ + j)) * QPDIM + 16 + l5 * 8);

    float mx = -1e30f;
    const int ibase = iq * 1024 + ih * 512;
    for (int cc = 0; cc < 16; ++cc) {
        const _Float16* qp = qg + (size_t)(ibase + cc * 32 + lj) * QPDIM + l5 * 8;
        half8_t qa0 = *(const half8_t*)qp;
        half8_t qa1 = *(const half8_t*)(qp + 16);
        floatx16 S = __builtin_amdgcn_mfma_f32_32x32x16_f16(
            qa0, kb0, (floatx16){0.f}, 0, 0, 0);
        S = __builtin_amdgcn_mfma_f32_32x32x16_f16(qa1, kb1, S, 0, 0, 0);
        #pragma unroll
        for (int r = 0; r < 16; ++r) mx = fmaxf(mx, S[r]);
    }
    mx = fmaxf(mx, __shfl_xor(mx, 32));
    if (lane < 32) wmax[w][lane] = mx;
    __syncthreads();
    if (t < 64) {
        const int jt3 = t >> 5, c = t & 31;
        ms4[(size_t)iq * (NBATCH * NSEQ) + (size_t)b * NSEQ
            + jblk * 64 + jt3 * 32 + c] = fmaxf(wmax[jt3][c], wmax[jt3 + 2][c]);
    }
}

// ---------------------------------------------------------------------------
// K3: attn. grid = 512 (4b x 64 jblk x 2 jh -> 32-j blocks), 256 thr
// (4 waves = ih4), 2 blk/CU. NO LDS in main loop, NO barriers: va read
// directly from L2-resident vHT. Wave ih: S quarter (32j x 32i of 128-i
// tile, C-init=-mfix) -> exp2 -> permlane transform -> PV all 256 c.
// ---------------------------------------------------------------------------
__global__ __launch_bounds__(256, 2) void attn_kernel(
    const _Float16* __restrict__ qH, const _Float16* __restrict__ kH,
    const _Float16* __restrict__ vHT, const float* __restrict__ ms4,
    const float* __restrict__ x, const float* __restrict__ gamma,
    float* __restrict__ out)
{
    __shared__ float fred[2][8192];   // 64 KB, epilogue merge only
    __shared__ float lred[4][32];     // [ih][j] denominator partials

    const int blk  = blockIdx.x;
    const int slot = blk & 7;         // XCD affinity: one (b, jh) per XCD
    const int b    = slot >> 1;
    const int jh   = slot & 1;
    const int jblk = blk >> 3;        // 0..63
    const int j0   = jblk * 64 + jh * 32;
    const int t    = threadIdx.x;
    const int lane = t & 63;
    const int l5   = lane >> 5;
    const int lj   = lane & 31;
    const int ih   = t >> 6;          // 0..3 (32-i slice of each 128-i tile)

    const _Float16* qg = qH + (size_t)b * NSEQ * QPDIM;
    const _Float16* vg = vHT + (size_t)b * CDIM * NSEQ;

    // persistent K frags (k of this block's 32-j tile)
    const int jme = j0 + lj;
    const half8_t kb0 = *(const half8_t*)(
        kH + ((size_t)(b * NSEQ + jme)) * QPDIM + l5 * 8);
    const half8_t kb1 = *(const half8_t*)(
        kH + ((size_t)(b * NSEQ + jme)) * QPDIM + 16 + l5 * 8);
    const float* msb = ms4 + (size_t)b * NSEQ + jme;
    const float mfix = fmaxf(
        fmaxf(msb[0], msb[NBATCH * NSEQ]),
        fmaxf(msb[2 * NBATCH * NSEQ], msb[3 * NBATCH * NSEQ]));
    floatx16 Sinit;
    #pragma unroll
    for (int r = 0; r < 16; ++r) Sinit[r] = -mfix;

    floatx16 acc[8];
    #pragma unroll
    for (int ct = 0; ct < 8; ++ct) acc[ct] = (floatx16){0.f};
    float lp = 0.0f;

    const _Float16* qb = qg + (size_t)(ih * 32 + lj) * QPDIM + l5 * 8;

    for (int i0 = 0; i0 < NSEQ; i0 += 128) {
        const int ib = i0 + ih * 32;   // wave's 32-i slice

        // q frags (L2-hot, 1 MB table)
        half8_t qa0 = *(const half8_t*)(qb + (size_t)i0 * QPDIM);
        half8_t qa1 = *(const half8_t*)(qb + (size_t)i0 * QPDIM + 16);

        // va batch A (ct 0..3): issue early, consumed by PV half 1
        half8_t vaA[4][2];
        #pragma unroll
        for (int ct = 0; ct < 4; ++ct) {
            const _Float16* vp = vg + (size_t)(ct * 32 + lj) * NSEQ + ib + l5 * 8;
            vaA[ct][0] = *(const half8_t*)(vp);
            vaA[ct][1] = *(const half8_t*)(vp + 16);
        }

        // ---- S quarter: D[m=i][n=j], lane j = lj, regs = i; C-init=-mfix --
        floatx16 S = __builtin_amdgcn_mfma_f32_32x32x16_f16(
            qa0, kb0, Sinit, 0, 0, 0);
        S = __builtin_amdgcn_mfma_f32_32x32x16_f16(qa1, kb1, S, 0, 0, 0);

        // exp2 + pack + denominator partial (log2 domain)
        H8 lo, hi;
        float ls = 0.0f;
        #pragma unroll
        for (int p = 0; p < 4; ++p) {
            float pa = __builtin_amdgcn_exp2f(S[2 * p]);
            float pb = __builtin_amdgcn_exp2f(S[2 * p + 1]);
            ls += pa + pb;
            lo.h2[p] = pack_f16(pa, pb);
        }
        #pragma unroll
        for (int p = 0; p < 4; ++p) {
            float pa = __builtin_amdgcn_exp2f(S[8 + 2 * p]);
            float pb = __builtin_amdgcn_exp2f(S[8 + 2 * p + 1]);
            ls += pa + pb;
            hi.h2[p] = pack_f16(pa, pb);
        }
        lp += ls;

        H8 Pa, Pb;
        transformP(lo, hi, Pa, Pb, l5);

        // va batch B (ct 4..7): in flight under PV half 1
        half8_t vaB[4][2];
        #pragma unroll
        for (int ct = 0; ct < 4; ++ct) {
            const _Float16* vp =
                vg + (size_t)((ct + 4) * 32 + lj) * NSEQ + ib + l5 * 8;
            vaB[ct][0] = *(const half8_t*)(vp);
            vaB[ct][1] = *(const half8_t*)(vp + 16);
        }

        // ---- PV: acc[ct] (D[m=c][n=j]) += v(A) . P(B), all 256 c ----
        __builtin_amdgcn_s_setprio(1);
        #pragma unroll
        for (int ct = 0; ct < 4; ++ct) {
            acc[ct] = __builtin_amdgcn_mfma_f32_32x32x16_f16(
                vaA[ct][0], Pa.h8, acc[ct], 0, 0, 0);
            acc[ct] = __builtin_amdgcn_mfma_f32_32x32x16_f16(
                vaA[ct][1], Pb.h8, acc[ct], 0, 0, 0);
        }
        #pragma unroll
        for (int ct = 0; ct < 4; ++ct) {
            acc[ct + 4] = __builtin_amdgcn_mfma_f32_32x32x16_f16(
                vaB[ct][0], Pa.h8, acc[ct + 4], 0, 0, 0);
            acc[ct + 4] = __builtin_amdgcn_mfma_f32_32x32x16_f16(
                vaB[ct][1], Pb.h8, acc[ct + 4], 0, 0, 0);
        }
        __builtin_amdgcn_s_setprio(0);
    }

    // ---- denominator partials ----
    lp += __shfl_xor(lp, 32);
    if (lane < 32) lred[ih][lane] = lp;
    __syncthreads();   // first barrier in the kernel

    // ---- 2-round merge across ih (pairs (0,1),(2,3), then cross) ----
    if (ih & 1) {
        float* rg = fred[ih >> 1];
        #pragma unroll
        for (int ct = 0; ct < 8; ++ct)
            #pragma unroll
            for (int reg = 0; reg < 16; ++reg) {
                const int crow = (reg & 3) + 8 * (reg >> 2) + 4 * l5;
                rg[(ct * 32 + crow) * 32 + lj] = acc[ct][reg];
            }
    }
    __syncthreads();
    if (!(ih & 1)) {
        float* rg = fred[ih >> 1];
        #pragma unroll
        for (int ct = 0; ct < 8; ++ct)
            #pragma unroll
            for (int reg = 0; reg < 16; ++reg) {
                const int crow = (reg & 3) + 8 * (reg >> 2) + 4 * l5;
                acc[ct][reg] += rg[(ct * 32 + crow) * 32 + lj];
            }
    }
    __syncthreads();
    // Round B: ih0 writes ct4..7 -> fred[0]; ih2 writes ct0..3 -> fred[1]
    if (ih == 0) {
        float* rg = fred[0];
        #pragma unroll
        for (int ct = 4; ct < 8; ++ct)
            #pragma unroll
            for (int reg = 0; reg < 16; ++reg) {
                const int crow = (reg & 3) + 8 * (reg >> 2) + 4 * l5;
                rg[(ct * 32 + crow) * 32 + lj] = acc[ct][reg];
            }
    } else if (ih == 2) {
        float* rg = fred[1];
        #pragma unroll
        for (int ct = 0; ct < 4; ++ct)
            #pragma unroll
            for (int reg = 0; reg < 16; ++reg) {
                const int crow = (reg & 3) + 8 * (reg >> 2) + 4 * l5;
                rg[(ct * 32 + crow) * 32 + lj] = acc[ct][reg];
            }
    }
    __syncthreads();
    // Final stores: LITERAL ct bounds per branch (no runtime acc index).
    if (ih == 0) {
        const float lsum = lred[0][lj] + lred[1][lj] + lred[2][lj] + lred[3][lj];
        const float rv = gamma[0] / lsum;
        float* rg = fred[1];
        #pragma unroll
        for (int ct = 0; ct < 4; ++ct) {
            #pragma unroll
            for (int reg = 0; reg < 16; ++reg) {
                const int crow = (reg & 3) + 8 * (reg >> 2) + 4 * l5;
                const int c_ = ct * 32 + crow;
                const size_t off = ((size_t)(b * CDIM + c_)) * NSEQ + jme;
                const float sum =
                    acc[ct][reg] + rg[(ct * 32 + crow) * 32 + lj];
                out[off] = sum * rv + x[off];
            }
        }
    } else if (ih == 2) {
        const float lsum = lred[0][lj] + lred[1][lj] + lred[2][lj] + lred[3][lj];
        const float rv = gamma[0] / lsum;
        float* rg = fred[0];
        #pragma unroll
        for (int ct = 4; ct < 8; ++ct) {
            #pragma unroll
            for (int reg = 0; reg < 16; ++reg) {
                const int crow = (reg & 3) + 8 * (reg >> 2) + 4 * l5;
                const int c_ = ct * 32 + crow;
                const size_t off = ((size_t)(b * CDIM + c_)) * NSEQ + jme;
                const float sum =
                    acc[ct][reg] + rg[(ct * 32 + crow) * 32 + lj];
                out[off] = sum * rv + x[off];
            }
        }
    }
}

extern "C" void kernel_launch(void* const* d_in, const int* in_sizes, int n_in,
                              void* d_out, int out_size, void* d_ws, size_t ws_size,
                              hipStream_t stream) {
    const float* x     = (const float*)d_in[0];
    const float* Wq    = (const float*)d_in[1];
    const float* bq    = (const float*)d_in[2];
    const float* Wk    = (const float*)d_in[3];
    const float* bk    = (const float*)d_in[4];
    const float* Wv    = (const float*)d_in[5];
    const float* bv    = (const float*)d_in[6];
    const float* gamma = (const float*)d_in[7];
    float* out = (float*)d_out;

    _Float16* w16 = (_Float16*)d_ws;
    _Float16* qH  = w16;                                        // 1 MB
    _Float16* kH  = qH + (size_t)NBATCH * NSEQ * QPDIM;         // 1 MB
    _Float16* vHT = kH + (size_t)NBATCH * NSEQ * QPDIM;         // 8 MB
    _Float16* wH  = vHT + (size_t)NBATCH * CDIM * NSEQ;         // 160 KB
    float*    ms4 = (float*)(wH + (size_t)320 * 256);           // 256 KB

    wprep_kernel<<<40, 256, 0, stream>>>(Wv, Wq, Wk, wH);
    qkv_kernel<<<512, 256, 0, stream>>>(x, wH, bq, bk, bv, qH, kH, vHT);
    mpass_kernel<<<1024, 256, 0, stream>>>(qH, kH, ms4);
    attn_kernel<<<512, 256, 0, stream>>>(qH, kH, vHT, ms4, x, gamma, out);
}

// Round 10
// 162.892 us; speedup vs baseline: 1.4958x; 1.4383x over previous
//
#include <hip/hip_runtime.h>
#include <hip/hip_bf16.h>
#include <math.h>

// B=4, C=256, N=4096, QP=32.
// ws: qH[b][n][32] f16 (PRE-SCALED by log2e), kH[b][n][32] f16,
//     vHT[b][c][n] f16, wH[320][256] f16 (Wq rows scaled), ms4[4][b][n] f32.
// K0 wprep: W->f16 (+log2e on Wq rows).
// K1 qkv: MFMA GEMM, 32-n tiles (512 blocks, 2 blk/CU).
// K2 mpass: partial col-max of S' (log2 domain); max3-tree reduction.
// K3 attn: r6 structure VERBATIM (best measured: 64.4 us attn, 163.7 total)
//   + ONE fix: q-prefetch issued right after the S-MFMAs (its only readers)
//   instead of just before the barrier -- __syncthreads drains vmcnt(0), so
//   late-issued q loads exposed full L2 latency every iteration.
//   [r7/r8/r9 lesson: structure rewrites (free-run vmcnt, va-reuse, no-LDS)
//   all regressed >=1.7x; per-lane strided global reads uncoalesce (r9),
//   inline-asm waitcnt defeats the compiler's waitcnt pass (r7).]

#define NBATCH 4
#define CDIM   256
#define NSEQ   4096
#define QPDIM  32
#define LOG2E  1.44269504088896340736f

typedef _Float16 half8_t  __attribute__((ext_vector_type(8)));
typedef _Float16 half2_t  __attribute__((ext_vector_type(2)));
typedef float    floatx4  __attribute__((ext_vector_type(4)));
typedef float    floatx16 __attribute__((ext_vector_type(16)));

union H8 { half8_t h8; half2_t h2[4]; int i32[4]; };

__device__ inline half2_t pack_f16(float a, float b) {
    return __builtin_bit_cast(half2_t, __builtin_amdgcn_cvt_pkrtz(a, b));
}

// ---------------------------------------------------------------------------
// K0: W -> f16, Wq rows scaled by log2e. 40 blocks x 256 thr x 8 elems.
// ---------------------------------------------------------------------------
__global__ __launch_bounds__(256) void wprep_kernel(
    const float* __restrict__ Wv, const float* __restrict__ Wq,
    const float* __restrict__ Wk, _Float16* __restrict__ wH)
{
    const int idx = blockIdx.x * 256 + threadIdx.x;
    const int e = idx * 8;
    const int r = e >> 8, c = e & 255;
    const float* src;
    float scale = 1.0f;
    if (r < 256)      src = Wv + (size_t)r * 256 + c;
    else if (r < 288) { src = Wq + (size_t)(r - 256) * 256 + c; scale = LOG2E; }
    else              src = Wk + (size_t)(r - 288) * 256 + c;
    float4 f0 = ((const float4*)src)[0];
    float4 f1 = ((const float4*)src)[1];
    half8_t h;
    h[0] = (_Float16)(f0.x * scale); h[1] = (_Float16)(f0.y * scale);
    h[2] = (_Float16)(f0.z * scale); h[3] = (_Float16)(f0.w * scale);
    h[4] = (_Float16)(f1.x * scale); h[5] = (_Float16)(f1.y * scale);
    h[6] = (_Float16)(f1.z * scale); h[7] = (_Float16)(f1.w * scale);
    *(half8_t*)(wH + (size_t)r * 256 + c) = h;
}

// ---------------------------------------------------------------------------
// K1: qkv GEMM. grid = 4b x 128 nt(32 n) = 512 blocks, 256 thr (4 waves).
// ---------------------------------------------------------------------------
__global__ __launch_bounds__(256, 2) void qkv_kernel(
    const float* __restrict__ x, const _Float16* __restrict__ wH,
    const float* __restrict__ bq, const float* __restrict__ bk,
    const float* __restrict__ bv,
    _Float16* __restrict__ qH, _Float16* __restrict__ kH,
    _Float16* __restrict__ vHT)
{
    __shared__ _Float16 xT[32][264];   // [n][c]

    const int blk  = blockIdx.x;
    const int slot = blk & 7;
    const int b    = slot >> 1;
    const int n0   = (((blk >> 3) << 1) | (slot & 1)) << 5;  // 32-n tile
    const int t    = threadIdx.x;
    const int w    = t >> 6;
    const int lane = t & 63;
    const int quad = lane >> 4;
    const int col  = lane & 15;

    // ---- stage x[b, :, n0..n0+31] transposed -> f16 ----
    {
        const int crow0 = t >> 3;          // 0..31
        const int npart = t & 7;           // 8 lanes sweep 32 n
        #pragma unroll
        for (int pass = 0; pass < 8; ++pass) {
            const int c = pass * 32 + crow0;
            float4 f = *(const float4*)(
                x + ((size_t)(b * CDIM + c)) * NSEQ + n0 + npart * 4);
            xT[npart * 4 + 0][c] = (_Float16)f.x;
            xT[npart * 4 + 1][c] = (_Float16)f.y;
            xT[npart * 4 + 2][c] = (_Float16)f.z;
            xT[npart * 4 + 3][c] = (_Float16)f.w;
        }
    }
    __syncthreads();

    // ---- GEMM: wave w -> rows w*80 .. +79 (5 m-tiles of 16), 32 n ----
    const int r0 = w * 80;
    floatx4 acc[5][2];
    #pragma unroll
    for (int mt = 0; mt < 5; ++mt)
        #pragma unroll
        for (int nt = 0; nt < 2; ++nt)
            acc[mt][nt] = (floatx4){0.f, 0.f, 0.f, 0.f};

    #pragma unroll
    for (int ks = 0; ks < 8; ++ks) {
        half8_t bf[2];
        #pragma unroll
        for (int nt = 0; nt < 2; ++nt)
            bf[nt] = *(const half8_t*)&xT[nt * 16 + col][ks * 32 + quad * 8];
        #pragma unroll
        for (int mt = 0; mt < 5; ++mt) {
            half8_t a = *(const half8_t*)(
                wH + (size_t)(r0 + mt * 16 + col) * 256 + ks * 32 + quad * 8);
            #pragma unroll
            for (int nt = 0; nt < 2; ++nt)
                acc[mt][nt] = __builtin_amdgcn_mfma_f32_16x16x32_f16(
                    a, bf[nt], acc[mt][nt], 0, 0, 0);
        }
    }

    // ---- epilogue ----
    #pragma unroll
    for (int mt = 0; mt < 5; ++mt) {
        const int gbase = r0 + mt * 16;
        const float* bp; int rl; float bscale = 1.0f;
        if (gbase < 256)      { bp = bv; rl = gbase; }
        else if (gbase < 288) { bp = bq; rl = gbase - 256; bscale = LOG2E; }
        else                  { bp = bk; rl = gbase - 288; }
        #pragma unroll
        for (int reg = 0; reg < 4; ++reg) {
            const int rr = rl + quad * 4 + reg;
            const float bias = bp[rr] * bscale;
            #pragma unroll
            for (int nt = 0; nt < 2; ++nt) {
                const int n = n0 + nt * 16 + col;
                const float val = acc[mt][nt][reg] + bias;
                if (gbase < 256)
                    vHT[((size_t)(b * CDIM + rr)) * NSEQ + n] = (_Float16)val;
                else if (gbase < 288)
                    qH[((size_t)(b * NSEQ + n)) * QPDIM + rr] = (_Float16)val;
                else
                    kH[((size_t)(b * NSEQ + n)) * QPDIM + rr] = (_Float16)val;
            }
        }
    }
}

// ---------------------------------------------------------------------------
// K2: mpass partial col-max (log2 domain). grid = 4iq x 4b x 64 jblk = 1024.
// max3-tree reduction (v_max3_f32 fusion) replaces the 15-op serial chain.
// ---------------------------------------------------------------------------
__global__ __launch_bounds__(256, 4) void mpass_kernel(
    const _Float16* __restrict__ qH, const _Float16* __restrict__ kH,
    float* __restrict__ ms4)
{
    __shared__ float wmax[4][32];

    const int blk  = blockIdx.x;
    const int slot = blk & 7;
    const int b    = slot >> 1;
    const int idx  = ((blk >> 3) << 1) | (slot & 1);
    const int jblk = idx & 63;
    const int iq   = idx >> 6;
    const int t    = threadIdx.x;
    const int w    = t >> 6;
    const int lane = t & 63;
    const int l5   = lane >> 5;
    const int lj   = lane & 31;
    const int jt   = w & 1, ih = w >> 1;

    const _Float16* qg = qH + (size_t)b * NSEQ * QPDIM;
    const int j = jblk * 64 + jt * 32 + lj;
    const half8_t kb0 = *(const half8_t*)(
        kH + ((size_t)(b * NSEQ + j)) * QPDIM + l5 * 8);
    const half8_t kb1 = *(const half8_t*)(
        kH + ((size_t)(b * NSEQ + j)) * QPDIM + 16 + l5 * 8);

    float mx = -1e30f;
    const int ibase = iq * 1024 + ih * 512;
    for (int cc = 0; cc < 16; ++cc) {
        const _Float16* qp = qg + (size_t)(ibase + cc * 32 + lj) * QPDIM + l5 * 8;
        half8_t qa0 = *(const half8_t*)qp;
        half8_t qa1 = *(const half8_t*)(qp + 16);
        floatx16 S = __builtin_amdgcn_mfma_f32_32x32x16_f16(
            qa0, kb0, (floatx16){0.f}, 0, 0, 0);
        S = __builtin_amdgcn_mfma_f32_32x32x16_f16(qa1, kb1, S, 0, 0, 0);
        // max3 tree: 5 triples + combine (fuses to v_max3_f32), depth ~4
        float t0 = fmaxf(fmaxf(S[0],  S[1]),  S[2]);
        float t1 = fmaxf(fmaxf(S[3],  S[4]),  S[5]);
        float t2 = fmaxf(fmaxf(S[6],  S[7]),  S[8]);
        float t3 = fmaxf(fmaxf(S[9],  S[10]), S[11]);
        float t4 = fmaxf(fmaxf(S[12], S[13]), S[14]);
        mx = fmaxf(mx, fmaxf(fmaxf(fmaxf(t0, t1), fmaxf(t2, t3)),
                             fmaxf(t4, S[15])));
    }
    mx = fmaxf(mx, __shfl_xor(mx, 32));
    if (lane < 32) wmax[w][lane] = mx;
    __syncthreads();
    if (t < 64) {
        const int jt3 = t >> 5, c = t & 31;
        ms4[(size_t)iq * (NBATCH * NSEQ) + (size_t)b * NSEQ
            + jblk * 64 + jt3 * 32 + c] = fmaxf(wmax[jt3][c], wmax[jt3 + 2][c]);
    }
}

// ---------------------------------------------------------------------------
// K3: attn. grid = 256 (4b x 64 jblk(64j)), 512 thr (8 waves = jh2 x ih4),
// 128-i tiles (32 iters). Wave (jh, ih): S quarter (32j x 32i, C-init=-mfix)
// -> exp2 (+denominator adds) -> permlane32 transform -> PV over ALL 256 c
// (8 ct, acc 8x16). Zero S duplication. v via swizzled global_load_lds dbuf.
// q-prefetch issued right after S-MFMAs (covered by exp2+PV before barrier).
// ---------------------------------------------------------------------------
__global__ __launch_bounds__(512, 1) void attn_kernel(
    const _Float16* __restrict__ qH, const _Float16* __restrict__ kH,
    const _Float16* __restrict__ vHT, const float* __restrict__ ms4,
    const float* __restrict__ x, const float* __restrict__ gamma,
    float* __restrict__ out)
{
    __shared__ _Float16 vbuf[2][32768];  // [buf][4096 units of 16B] (128 KB)
    __shared__ float lred[2][4][32];     // [jh][ih][j]

    const int blk  = blockIdx.x;
    const int slot = blk & 7;
    const int b    = slot >> 1;
    const int jblk = ((blk >> 3) << 1) | (slot & 1);  // 0..63
    const int j0   = jblk << 6;
    const int t    = threadIdx.x;
    const int w    = t >> 6;                          // 0..7
    const int lane = t & 63;
    const int l5   = lane >> 5;
    const int lj   = lane & 31;
    const int jh   = w & 1;
    const int ih   = w >> 1;                          // 0..3 (32-i slice)

    const _Float16* qg = qH + (size_t)b * NSEQ * QPDIM;
    const _Float16* vg = vHT + (size_t)b * CDIM * NSEQ;

    // persistent S B-frags (k of this wave's 32-j tile)
    const int jme = j0 + jh * 32 + lj;
    const half8_t kb0 = *(const half8_t*)(
        kH + ((size_t)(b * NSEQ + jme)) * QPDIM + l5 * 8);
    const half8_t kb1 = *(const half8_t*)(
        kH + ((size_t)(b * NSEQ + jme)) * QPDIM + 16 + l5 * 8);
    const float* msb = ms4 + (size_t)b * NSEQ + jme;
    const float mfix = fmaxf(
        fmaxf(msb[0], msb[NBATCH * NSEQ]),
        fmaxf(msb[2 * NBATCH * NSEQ], msb[3 * NBATCH * NSEQ]));
    floatx16 Sinit;
    #pragma unroll
    for (int r = 0; r < 16; ++r) Sinit[r] = -mfix;

    floatx16 acc[8];
    #pragma unroll
    for (int ct = 0; ct < 8; ++ct) acc[ct] = (floatx16){0.f};
    float lp = 0.0f;

    // v DMA: 4096 units of 16B per buffer (256 c x 16 chunks of 8 i).
    // wave w covers units [w*512, +512); lane gets 8. XOR-swizzled chunks.
    #define DMA_V(i0_, buf_)                                                   \
        {                                                                      \
            _Pragma("unroll")                                                  \
            for (int g = 0; g < 8; ++g) {                                      \
                const int uu = w * 512 + g * 64 + lane;                        \
                const int cl = uu >> 4;                                        \
                const int ck = (uu & 15) ^ (cl & 7);                           \
                const _Float16* src =                                          \
                    vg + (size_t)cl * NSEQ + (i0_) + ck * 8;                   \
                __builtin_amdgcn_global_load_lds(                              \
                    (const __attribute__((address_space(1))) void*)src,        \
                    (__attribute__((address_space(3))) void*)                  \
                        (&vbuf[buf_][(w * 512 + g * 64) * 8]),                 \
                    16, 0, 0);                                                 \
            }                                                                  \
        }

    DMA_V(0, 0);
    const _Float16* qb = qg + (size_t)(ih * 32 + lj) * QPDIM + l5 * 8;
    half8_t qa0 = *(const half8_t*)(qb);
    half8_t qa1 = *(const half8_t*)(qb + 16);

    int cur = 0;
    for (int i0 = 0; i0 < NSEQ; i0 += 128) {
        __syncthreads();   // vbuf[cur] DMA'd; prev reads of vbuf[cur^1] done
        if (i0 + 128 < NSEQ) DMA_V(i0 + 128, cur ^ 1);

        // ---- S quarter: D[m=i][n=j], lane j = lj, regs = i; C-init=-mfix --
        floatx16 S = __builtin_amdgcn_mfma_f32_32x32x16_f16(
            qa0, kb0, Sinit, 0, 0, 0);
        S = __builtin_amdgcn_mfma_f32_32x32x16_f16(qa1, kb1, S, 0, 0, 0);

        // prefetch next q frags EARLY: issued here (only readers of qa are
        // the S-MFMAs above), so exp2+transform+PV covers L2 latency before
        // the barrier's vmcnt(0) drain. (r6 issued them just before the
        // barrier -> exposed ~200-400 cyc stall per wave per iter.)
        if (i0 + 128 < NSEQ) {
            qa0 = *(const half8_t*)(qb + (size_t)(i0 + 128) * QPDIM);
            qa1 = *(const half8_t*)(qb + (size_t)(i0 + 128) * QPDIM + 16);
        }

        // exp2 + pack + denominator partial (log2 domain)
        H8 lo, hi;
        float ls = 0.0f;
        #pragma unroll
        for (int p = 0; p < 4; ++p) {
            float pa = __builtin_amdgcn_exp2f(S[2 * p]);
            float pb = __builtin_amdgcn_exp2f(S[2 * p + 1]);
            ls += pa + pb;
            lo.h2[p] = pack_f16(pa, pb);
        }
        #pragma unroll
        for (int p = 0; p < 4; ++p) {
            float pa = __builtin_amdgcn_exp2f(S[8 + 2 * p]);
            float pb = __builtin_amdgcn_exp2f(S[8 + 2 * p + 1]);
            ls += pa + pb;
            hi.h2[p] = pack_f16(pa, pb);
        }
        lp += ls;

        // D -> B-operand transform.
        // v_permlane32_swap(a,b): ret0 = {a.lo, b.lo}, ret1 = {a.hi, b.hi}
        H8 P0, P1;   // B-operand frags: k = i 0..15 / 16..31 of wave's chunk
#if __has_builtin(__builtin_amdgcn_permlane32_swap)
        {
            auto r0p = __builtin_amdgcn_permlane32_swap(
                (unsigned)lo.i32[0], (unsigned)lo.i32[2], false, false);
            P0.i32[0] = (int)r0p[0]; P0.i32[2] = (int)r0p[1];
            auto r1p = __builtin_amdgcn_permlane32_swap(
                (unsigned)lo.i32[1], (unsigned)lo.i32[3], false, false);
            P0.i32[1] = (int)r1p[0]; P0.i32[3] = (int)r1p[1];
            auto r2p = __builtin_amdgcn_permlane32_swap(
                (unsigned)hi.i32[0], (unsigned)hi.i32[2], false, false);
            P1.i32[0] = (int)r2p[0]; P1.i32[2] = (int)r2p[1];
            auto r3p = __builtin_amdgcn_permlane32_swap(
                (unsigned)hi.i32[1], (unsigned)hi.i32[3], false, false);
            P1.i32[1] = (int)r3p[0]; P1.i32[3] = (int)r3p[1];
        }
#else
        {
            H8 shl, shh;
            #pragma unroll
            for (int r = 0; r < 4; ++r) {
                shl.i32[r] = __shfl_xor(lo.i32[r], 32);
                shh.i32[r] = __shfl_xor(hi.i32[r], 32);
            }
            const bool high = (l5 != 0);
            P0.i32[0] = high ? shl.i32[2] : lo.i32[0];
            P0.i32[1] = high ? shl.i32[3] : lo.i32[1];
            P0.i32[2] = high ? lo.i32[2]  : shl.i32[0];
            P0.i32[3] = high ? lo.i32[3]  : shl.i32[1];
            P1.i32[0] = high ? shh.i32[2] : hi.i32[0];
            P1.i32[1] = high ? shh.i32[3] : hi.i32[1];
            P1.i32[2] = high ? hi.i32[2]  : shh.i32[0];
            P1.i32[3] = high ? hi.i32[3]  : shh.i32[1];
        }
#endif

        // ---- PV: acc[ct] (D[m=c][n=j]) += v(A) . P(B), all 256 c ----
        __builtin_amdgcn_s_setprio(1);
        #pragma unroll
        for (int ct = 0; ct < 8; ++ct) {
            const int cl = ct * 32 + lj;
            const int ic0 = (ih * 4 + 0 + l5) ^ (cl & 7);   // ks=0 chunk
            const int ic1 = (ih * 4 + 2 + l5) ^ (cl & 7);   // ks=1 chunk
            half8_t va0 = *(const half8_t*)&vbuf[cur][(cl * 16 + ic0) * 8];
            half8_t va1 = *(const half8_t*)&vbuf[cur][(cl * 16 + ic1) * 8];
            acc[ct] = __builtin_amdgcn_mfma_f32_32x32x16_f16(
                va0, P0.h8, acc[ct], 0, 0, 0);
            acc[ct] = __builtin_amdgcn_mfma_f32_32x32x16_f16(
                va1, P1.h8, acc[ct], 0, 0, 0);
        }
        __builtin_amdgcn_s_setprio(0);

        cur ^= 1;
    }

    // ---- denominator: merge l5 pair; lred[jh][ih][j] ----
    lp += __shfl_xor(lp, 32);
    if (lane < 32) lred[jh][ih][lane] = lp;
    __syncthreads();   // all PV reads of vbuf done before fred overwrite

    // ---- cross-ih reduction (2 rounds) in fred = vbuf (4 x 32 KB regions)
    float* fred = (float*)vbuf;   // 32768 floats = 128 KB
    const int rA = jh * 2 + (ih >> 1);   // ih=1 -> jh*2, ih=3 -> jh*2+1
    if (ih & 1) {
        float* rg = fred + rA * 8192;
        #pragma unroll
        for (int ct = 0; ct < 8; ++ct)
            #pragma unroll
            for (int reg = 0; reg < 16; ++reg) {
                const int crow = (reg & 3) + 8 * (reg >> 2) + 4 * l5;
                rg[(ct * 32 + crow) * 32 + lj] = acc[ct][reg];
            }
    }
    __syncthreads();
    if (!(ih & 1)) {
        float* rg = fred + rA * 8192;
        #pragma unroll
        for (int ct = 0; ct < 8; ++ct)
            #pragma unroll
            for (int reg = 0; reg < 16; ++reg) {
                const int crow = (reg & 3) + 8 * (reg >> 2) + 4 * l5;
                acc[ct][reg] += rg[(ct * 32 + crow) * 32 + lj];
            }
    }
    __syncthreads();
    // Round B: ih0 <-> ih2 exchange halves (ih0 keeps ct0..3, ih2 ct4..7)
    if (ih == 0) {
        float* rg = fred + (jh * 2 + 0) * 8192;
        #pragma unroll
        for (int ct = 4; ct < 8; ++ct)
            #pragma unroll
            for (int reg = 0; reg < 16; ++reg) {
                const int crow = (reg & 3) + 8 * (reg >> 2) + 4 * l5;
                rg[(ct * 32 + crow) * 32 + lj] = acc[ct][reg];
            }
    } else if (ih == 2) {
        float* rg = fred + (jh * 2 + 1) * 8192;
        #pragma unroll
        for (int ct = 0; ct < 4; ++ct)
            #pragma unroll
            for (int reg = 0; reg < 16; ++reg) {
                const int crow = (reg & 3) + 8 * (reg >> 2) + 4 * l5;
                rg[(ct * 32 + crow) * 32 + lj] = acc[ct][reg];
            }
    }
    __syncthreads();
    // Final stores: LITERAL ct bounds in each branch (no runtime acc index).
    if (ih == 0) {
        const float lsum = lred[jh][0][lj] + lred[jh][1][lj]
                         + lred[jh][2][lj] + lred[jh][3][lj];
        const float rv = gamma[0] / lsum;
        float* rg = fred + (jh * 2 + 1) * 8192;
        #pragma unroll
        for (int ct = 0; ct < 4; ++ct) {
            #pragma unroll
            for (int reg = 0; reg < 16; ++reg) {
                const int crow = (reg & 3) + 8 * (reg >> 2) + 4 * l5;
                const int c_ = ct * 32 + crow;
                const size_t off = ((size_t)(b * CDIM + c_)) * NSEQ + jme;
                const float sum =
                    acc[ct][reg] + rg[(ct * 32 + crow) * 32 + lj];
                out[off] = sum * rv + x[off];
            }
        }
    } else if (ih == 2) {
        const float lsum = lred[jh][0][lj] + lred[jh][1][lj]
                         + lred[jh][2][lj] + lred[jh][3][lj];
        const float rv = gamma[0] / lsum;
        float* rg = fred + (jh * 2 + 0) * 8192;
        #pragma unroll
        for (int ct = 4; ct < 8; ++ct) {
            #pragma unroll
            for (int reg = 0; reg < 16; ++reg) {
                const int crow = (reg & 3) + 8 * (reg >> 2) + 4 * l5;
                const int c_ = ct * 32 + crow;
                const size_t off = ((size_t)(b * CDIM + c_)) * NSEQ + jme;
                const float sum =
                    acc[ct][reg] + rg[(ct * 32 + crow) * 32 + lj];
                out[off] = sum * rv + x[off];
            }
        }
    }
}

extern "C" void kernel_launch(void* const* d_in, const int* in_sizes, int n_in,
                              void* d_out, int out_size, void* d_ws, size_t ws_size,
                              hipStream_t stream) {
    const float* x     = (const float*)d_in[0];
    const float* Wq    = (const float*)d_in[1];
    const float* bq    = (const float*)d_in[2];
    const float* Wk    = (const float*)d_in[3];
    const float* bk    = (const float*)d_in[4];
    const float* Wv    = (const float*)d_in[5];
    const float* bv    = (const float*)d_in[6];
    const float* gamma = (const float*)d_in[7];
    float* out = (float*)d_out;

    _Float16* w16 = (_Float16*)d_ws;
    _Float16* qH  = w16;                                        // 1 MB
    _Float16* kH  = qH + (size_t)NBATCH * NSEQ * QPDIM;         // 1 MB
    _Float16* vHT = kH + (size_t)NBATCH * NSEQ * QPDIM;         // 8 MB
    _Float16* wH  = vHT + (size_t)NBATCH * CDIM * NSEQ;         // 160 KB
    float*    ms4 = (float*)(wH + (size_t)320 * 256);           // 256 KB

    wprep_kernel<<<40, 256, 0, stream>>>(Wv, Wq, Wk, wH);
    qkv_kernel<<<512, 256, 0, stream>>>(x, wH, bq, bk, bv, qH, kH, vHT);
    mpass_kernel<<<1024, 256, 0, stream>>>(qH, kH, ms4);
    attn_kernel<<<256, 512, 0, stream>>>(qH, kH, vHT, ms4, x, gamma, out);
}